// Round 20
// baseline (63.408 us; speedup 1.0000x reference)
//
#include <hip/hip_runtime.h>

#define N_NODES 100000
#define D 64
#define BIN_ROWS 64
#define NBINS 1563          // ceil(100000 / 64) fine bins (row>>6)
#define NC 196              // ceil(100000 / 512) coarse buckets (row>>9) = 8 fine bins each
#define PE 2048             // edges per hist/pass1 block
#define NTILES 6250         // 100000 / 16 node-tiles
#define XB 391              // xw blocks: 391*4 waves = 1564 waves, 4 tiles each (r17-proven)

typedef unsigned int u32;
typedef __attribute__((ext_vector_type(8))) short short8;   // 8 bf16 (4 VGPRs)
typedef __attribute__((ext_vector_type(4))) float f32x4;    // MFMA accumulator

__device__ __forceinline__ float bf16_to_f32(unsigned short u) {
    union { u32 i; float f; } c; c.i = ((u32)u) << 16; return c.f;
}
__device__ __forceinline__ unsigned short f32_to_bf16(float f) {
    union { float f; u32 i; } c; c.f = f;
    const u32 u = c.i;
    return (unsigned short)((u + 0x7FFFu + ((u >> 16) & 1u)) >> 16);
}
// HW packed convert (RNE), gfx950: v_cvt_pk_bf16_f32 — no builtin, asm only (T12/m240)
__device__ __forceinline__ short8 pack_bf16x8(float4 a, float4 b) {
    union { u32 w[4]; short8 s; } r;
    asm("v_cvt_pk_bf16_f32 %0, %1, %2" : "=v"(r.w[0]) : "v"(a.x), "v"(a.y));
    asm("v_cvt_pk_bf16_f32 %0, %1, %2" : "=v"(r.w[1]) : "v"(a.z), "v"(a.w));
    asm("v_cvt_pk_bf16_f32 %0, %1, %2" : "=v"(r.w[2]) : "v"(b.x), "v"(b.y));
    asm("v_cvt_pk_bf16_f32 %0, %1, %2" : "=v"(r.w[3]) : "v"(b.z), "v"(b.w));
    return r.s;
}

// ---------------- K1: per-block coarse histogram -> dense coarse2d[blk][NC] ----------------
__global__ __launch_bounds__(512) void histC_kernel(const int* __restrict__ erow,
                                                    int* __restrict__ coarse2d, int ne) {
    __shared__ int h[NC];
    const int tid = threadIdx.x;
    if (tid < NC) h[tid] = 0;
    __syncthreads();
    const int base = blockIdx.x * PE;
    const int end  = min(base + PE, ne);
    for (int e = base + tid; e < end; e += 512)
        atomicAdd(&h[erow[e] >> 9], 1);              // LDS, no-return
    __syncthreads();
    if (tid < NC) coarse2d[blockIdx.x * NC + tid] = h[tid];
}

// ---------------- K2: scanA — per-1024-chunk exclusive scan (coarse-major) + chunk sums ----------------
__global__ __launch_bounds__(256) void scanA_kernel(const int* __restrict__ coarse2d,
                                                    int* __restrict__ csc,
                                                    int* __restrict__ bsum,
                                                    int total, int npb) {
    __shared__ int sdat[256];
    const int tid  = threadIdx.x;
    const int base = blockIdx.x * 1024 + tid * 4;
    int v[4], sum = 0;
    int C = 0, blk = 0;
    if (base < total) { C = base / npb; blk = base - C * npb; }
#pragma unroll
    for (int k = 0; k < 4; ++k) {
        const int idx = base + k;
        v[k] = (idx < total) ? coarse2d[blk * NC + C] : 0;
        sum += v[k];
        if (++blk == npb) { blk = 0; ++C; }
    }
    sdat[tid] = sum;
    __syncthreads();
    for (int d = 1; d < 256; d <<= 1) {
        const int t = (tid >= d) ? sdat[tid - d] : 0;
        __syncthreads();
        sdat[tid] += t;
        __syncthreads();
    }
    int run = sdat[tid] - sum;
#pragma unroll
    for (int k = 0; k < 4; ++k) {
        const int idx = base + k;
        if (idx < total) csc[idx] = run;
        run += v[k];
    }
    if (tid == 255) bsum[blockIdx.x] = sdat[255];
}

// ---------------- K3: fused  pass1 coarse scatter (blocks < npb)  ||  MFMA xw (blocks >= npb) ----------------
__global__ __launch_bounds__(256) void xw_pass1_kernel(const float* __restrict__ x,
                                                       const float* __restrict__ W,
                                                       unsigned short* __restrict__ y,
                                                       const int* __restrict__ erow,
                                                       const int* __restrict__ ecol,
                                                       const float* __restrict__ eval_,
                                                       const int* __restrict__ csc,
                                                       const int* __restrict__ bsum,
                                                       uint2* __restrict__ pedge1,
                                                       int* __restrict__ cstart,
                                                       int ne, int npb, int nbA) {
    __shared__ int lcur[NC];                         // pass1 blocks only
    __shared__ int ps[128];                          // exclusive prefix of bsum chunks
    const int tid = threadIdx.x;

    if ((int)blockIdx.x < npb) {
        // ---- in-block exclusive scan of bsum (nbA <= 128) ----
        if (tid < 128) ps[tid] = (tid > 0 && tid - 1 < nbA) ? bsum[tid - 1] : 0;
        __syncthreads();
        for (int d = 1; d < 128; d <<= 1) {
            int t = 0;
            if (tid < 128 && tid >= d) t = ps[tid - d];
            __syncthreads();
            if (tid < 128) ps[tid] += t;
            __syncthreads();
        }

        // ---- pass1: coarse scatter, ~10-edge runs ----
        const int blk = blockIdx.x;
        if (tid < NC) {
            const int idx = tid * npb + blk;
            const int v = csc[idx] + ps[idx >> 10];
            lcur[tid] = v;
            if (blk == 0) cstart[tid] = v;           // coarse bucket global starts
        }
        if (blk == 0 && tid == 0) cstart[NC] = ne;
        __syncthreads();
        const int base = blk * PE;
        const int end  = min(base + PE, ne);
        for (int e = base + tid; e < end; e += 256) {
            const int r = erow[e];
            const int C = r >> 9;
            const int pos = atomicAdd(&lcur[C], 1);  // LDS-local rank
            int q = (int)(eval_[e] * 512.0f + 0.5f);
            q = (q > 511) ? 511 : q;
            uint2 pk;
            pk.x = ((u32)ecol[e] << 15) | ((u32)(r & 63) << 9) | (u32)q;
            pk.y = (u32)((r >> 6) & 7);              // fine bin within coarse bucket
            pedge1[pos] = pk;
        }
        return;
    }

    // ---- xw via MFMA (r16/r17-proven): 4 tiles per wave, no LDS ----
    const int gw = ((int)blockIdx.x - npb) * 4 + (tid >> 6);   // [0,1564)
    const int c  = tid & 15;
    const int q4 = (tid >> 4) & 3;

    const float4* Wv = (const float4*)W;
    short8 bfrag[4][2];
#pragma unroll
    for (int g = 0; g < 4; ++g) {
#pragma unroll
        for (int h = 0; h < 2; ++h) {
            const int bi = (16 * g + c) * 16 + 8 * h + 2 * q4;
            bfrag[g][h] = pack_bf16x8(Wv[bi], Wv[bi + 1]);
        }
    }

    const float4* Xv = (const float4*)x;
#pragma unroll
    for (int t = 0; t < 4; ++t) {
        const int tile = gw + 1564 * t;
        if (tile >= NTILES) break;
        const int n0 = tile * 16;

        const int ai = (n0 + c) * 16 + 2 * q4;
        const short8 a0 = pack_bf16x8(Xv[ai],     Xv[ai + 1]);       // k 0..31
        const short8 a1 = pack_bf16x8(Xv[ai + 8], Xv[ai + 9]);       // k 32..63

        f32x4 acc0 = {0.f, 0.f, 0.f, 0.f}, acc1 = acc0, acc2 = acc0, acc3 = acc0;
        acc0 = __builtin_amdgcn_mfma_f32_16x16x32_bf16(a0, bfrag[0][0], acc0, 0, 0, 0);
        acc1 = __builtin_amdgcn_mfma_f32_16x16x32_bf16(a0, bfrag[1][0], acc1, 0, 0, 0);
        acc2 = __builtin_amdgcn_mfma_f32_16x16x32_bf16(a0, bfrag[2][0], acc2, 0, 0, 0);
        acc3 = __builtin_amdgcn_mfma_f32_16x16x32_bf16(a0, bfrag[3][0], acc3, 0, 0, 0);
        acc0 = __builtin_amdgcn_mfma_f32_16x16x32_bf16(a1, bfrag[0][1], acc0, 0, 0, 0);
        acc1 = __builtin_amdgcn_mfma_f32_16x16x32_bf16(a1, bfrag[1][1], acc1, 0, 0, 0);
        acc2 = __builtin_amdgcn_mfma_f32_16x16x32_bf16(a1, bfrag[2][1], acc2, 0, 0, 0);
        acc3 = __builtin_amdgcn_mfma_f32_16x16x32_bf16(a1, bfrag[3][1], acc3, 0, 0, 0);

        const int rbase = n0 + q4 * 4;
#pragma unroll
        for (int r = 0; r < 4; ++r) {
            y[(rbase + r) * D +  0 + c] = f32_to_bf16(acc0[r]);
            y[(rbase + r) * D + 16 + c] = f32_to_bf16(acc1[r]);
            y[(rbase + r) * D + 32 + c] = f32_to_bf16(acc2[r]);
            y[(rbase + r) * D + 48 + c] = f32_to_bf16(acc3[r]);
        }
    }
}

// ---------------- K4: pass2 — per-coarse-bucket fine sort; derives binStart locally ----------------
__global__ __launch_bounds__(512) void pass2_kernel(const uint2* __restrict__ pedge1,
                                                    const int* __restrict__ cstart,
                                                    u32* __restrict__ pedge,
                                                    int* __restrict__ binStart) {
    __shared__ int fh[8];
    __shared__ int fcur[8];
    const int tid = threadIdx.x;
    const int C   = blockIdx.x;
    const int s   = cstart[C];
    const int e   = cstart[C + 1];

    if (tid < 8) fh[tid] = 0;
    __syncthreads();
    for (int i = s + tid; i < e; i += 512)
        atomicAdd(&fh[pedge1[i].y], 1);              // LDS, no-return
    __syncthreads();
    if (tid == 0) {
        int run = s;
#pragma unroll
        for (int j = 0; j < 8; ++j) {
            fcur[j] = run;
            binStart[8 * C + j] = run;
            run += fh[j];
        }
        binStart[8 * C + 8] = run;
    }
    __syncthreads();
    for (int i = s + tid; i < e; i += 512) {
        const uint2 p = pedge1[i];
        const int pos = atomicAdd(&fcur[p.y], 1);    // single-writer-per-bin, coalesced runs
        pedge[pos] = p.x;
    }
}

// ---------------- K5: aggregate — r17-proven 16-deep body + wave work-stealing ----------------
__global__ __launch_bounds__(512) void aggregate_kernel(const int* __restrict__ binStart,
                                                        const u32* __restrict__ pedge,
                                                        const unsigned short* __restrict__ y,
                                                        const float* __restrict__ b,
                                                        float4* __restrict__ out4) {
    __shared__ int acc[BIN_ROWS * D];    // 16 KB
    __shared__ int nextBatch;
    const int tid = threadIdx.x;
    for (int i = tid; i < BIN_ROWS * D; i += 512) acc[i] = 0;

    const int bin  = blockIdx.x;
    const int lane = tid & 63;
    const int s    = binStart[bin];
    const int e    = binStart[bin + 1];
    if (tid == 0) nextBatch = s;
    __syncthreads();

    for (;;) {
        int bb0 = 0;
        if (lane == 0) bb0 = atomicAdd(&nextBatch, 16);      // wave pops a 16-edge batch
        const int bb = __builtin_amdgcn_readfirstlane(bb0);
        if (bb >= e) break;
        u32 u[16];
        if (bb + 16 <= e) {
#pragma unroll
            for (int j = 0; j < 16; ++j) u[j] = pedge[bb + j];   // uniform -> s_load
        } else {
#pragma unroll
            for (int j = 0; j < 16; ++j) {
                const int idx = bb + j;
                u[j] = (idx < e) ? pedge[idx] : 0u;              // pad adds 0
            }
        }
        unsigned short g[16];
#pragma unroll
        for (int j = 0; j < 16; ++j) {                           // 16 concurrent 128B gathers
            g[j] = y[(int)(u[j] >> 15) * D + lane];
        }
#pragma unroll
        for (int j = 0; j < 16; ++j) {
            const float vq = (float)(u[j] & 511u);               // val * 512
            const float yf = bf16_to_f32(g[j]);
            const int   qi = (int)(vq * yf * 512.0f);            // contribution * 2^18
            const int   r  = (int)((u[j] >> 9) & 63u);
            atomicAdd(&acc[r * D + lane], qi);                   // ds_add_u32 (native)
        }
    }
    __syncthreads();

    const int rowBase = bin * BIN_ROWS;
    const float INV = 1.0f / 262144.0f;
    for (int i = tid; i < BIN_ROWS * 16; i += 512) {
        const int rl = i >> 4, q = i & 15;
        const int row = rowBase + rl;
        if (row < N_NODES) {
            const int4   a  = ((const int4*)acc)[i];
            const float4 bv = ((const float4*)b)[q];
            out4[row * 16 + q] = make_float4((float)a.x * INV + bv.x,
                                             (float)a.y * INV + bv.y,
                                             (float)a.z * INV + bv.z,
                                             (float)a.w * INV + bv.w);
        }
    }
}

// ---------------- fallback (small ws): atomic scatter ----------------
__global__ __launch_bounds__(256) void init_out_kernel(const float* __restrict__ b,
                                                       float* __restrict__ out) {
    const int i = blockIdx.x * blockDim.x + threadIdx.x;
    const int total4 = N_NODES * D / 4;
    if (i < total4) {
        const float4* b4 = reinterpret_cast<const float4*>(b);
        reinterpret_cast<float4*>(out)[i] = b4[i & 15];
    }
}

__global__ __launch_bounds__(256) void scatter_kernel(const int* __restrict__ erow,
                                                      const int* __restrict__ ecol,
                                                      const float* __restrict__ eval_,
                                                      const unsigned short* __restrict__ y,
                                                      float* __restrict__ out, int ne) {
    const int e    = blockIdx.x * 4 + (threadIdx.x >> 6);
    const int lane = threadIdx.x & 63;
    if (e >= ne) return;
    atomicAdd(&out[erow[e] * D + lane], eval_[e] * bf16_to_f32(y[ecol[e] * D + lane]));
}

extern "C" void kernel_launch(void* const* d_in, const int* in_sizes, int n_in,
                              void* d_out, int out_size, void* d_ws, size_t ws_size,
                              hipStream_t stream) {
    const float* x     = (const float*)d_in[0];
    const int*   erow  = (const int*)  d_in[1];
    const int*   ecol  = (const int*)  d_in[2];
    const float* eval_ = (const float*)d_in[3];
    const float* W     = (const float*)d_in[4];
    const float* b     = (const float*)d_in[5];
    float*       out   = (float*)d_out;
    const int ne = in_sizes[1];

    char* ws = (char*)d_ws;
    // workspace layout (aligned)
    const size_t Y_OFF      = 0;            // 12,800,000 B
    const size_t PEDGE_OFF  = 12800000;     // 4,000,000 B (final u32)
    const size_t PEDGE1_OFF = 16800000;     // 8,000,000 B (coarse uint2)
    const size_t C2D_OFF    = 24800000;     // npb*NC*4 (<= 400,000 B)
    const size_t CSC_OFF    = 25200000;     // <= 400,000 B
    const size_t BSUM_OFF   = 25600000;     // 512 B
    const size_t CST_OFF    = 25600512;     // (NC+1)*4 -> 1,024 B
    const size_t BST_OFF    = 25601536;     // (8*NC+9)*4 -> 6,400 B
    const size_t TOTAL      = 25607936;

    unsigned short* y = (unsigned short*)(ws + Y_OFF);

    const int npb      = (ne + PE - 1) / PE;       // 489 @ 1M edges
    const int totalSc  = NC * npb;                 // 95,844
    const int nblocksA = (totalSc + 1023) / 1024;  // 94 (<= 128 for in-block prefix)

    if (ws_size >= TOTAL && npb <= 510 && ne <= 1000000 && nblocksA <= 128) {
        u32*   pedge    = (u32*)  (ws + PEDGE_OFF);
        uint2* pedge1   = (uint2*)(ws + PEDGE1_OFF);
        int*   coarse2d = (int*)  (ws + C2D_OFF);
        int*   csc      = (int*)  (ws + CSC_OFF);
        int*   bsum     = (int*)  (ws + BSUM_OFF);
        int*   cstart   = (int*)  (ws + CST_OFF);
        int*   binStart = (int*)  (ws + BST_OFF);

        // 1) per-block coarse histograms
        histC_kernel<<<npb, 512, 0, stream>>>(erow, coarse2d, ne);

        // 2) coarse-major exclusive scan (chunk-local; chunk prefix folded into pass1)
        scanA_kernel<<<nblocksA, 256, 0, stream>>>(coarse2d, csc, bsum, totalSc, npb);

        // 3) fused: pass1 coarse scatter (blocks [0,npb)) || MFMA xw (blocks [npb, npb+XB))
        xw_pass1_kernel<<<npb + XB, 256, 0, stream>>>(x, W, y, erow, ecol, eval_,
                                                      csc, bsum, pedge1, cstart, ne, npb, nblocksA);

        // 4) pass2: per-coarse-bucket fine sort (derives binStart)
        pass2_kernel<<<NC, 512, 0, stream>>>(pedge1, cstart, pedge, binStart);

        // 5) per-bin aggregation + bias (work-stealing waves)
        aggregate_kernel<<<NBINS, 512, 0, stream>>>(binStart, pedge, y, b, (float4*)out);
    } else {
        xw_pass1_kernel<<<XB, 256, 0, stream>>>(x, W, y, erow, ecol, eval_,
                                                (int*)ws, (int*)ws, (uint2*)ws, (int*)ws, 0, 0, 0);
        init_out_kernel<<<(N_NODES * D / 4 + 255) / 256, 256, 0, stream>>>(b, out);
        scatter_kernel<<<(ne + 3) / 4, 256, 0, stream>>>(erow, ecol, eval_, y, out, ne);
    }
}

// Round 21
// 61.904 us; speedup vs baseline: 1.0243x; 1.0243x over previous
//
#include <hip/hip_runtime.h>

#define N_NODES 100000
#define D 64
#define BIN_ROWS 64
#define NBINS 1563          // ceil(100000 / 64) fine bins (row>>6)
#define NC 196              // ceil(100000 / 512) coarse buckets (row>>9) = 8 fine bins each
#define PE 2048             // edges per hist/pass1 block
#define NTILES 6250         // 100000 / 16 node-tiles
#define XB 391              // xw blocks: 391*4 waves = 1564 waves, 4 tiles each (r17-proven)

typedef unsigned int u32;
typedef __attribute__((ext_vector_type(8))) short short8;   // 8 bf16 (4 VGPRs)
typedef __attribute__((ext_vector_type(4))) float f32x4;    // MFMA accumulator

__device__ __forceinline__ float bf16_to_f32(unsigned short u) {
    union { u32 i; float f; } c; c.i = ((u32)u) << 16; return c.f;
}
__device__ __forceinline__ unsigned short f32_to_bf16(float f) {
    union { float f; u32 i; } c; c.f = f;
    const u32 u = c.i;
    return (unsigned short)((u + 0x7FFFu + ((u >> 16) & 1u)) >> 16);
}
__device__ __forceinline__ short8 pack_bf16x8(float4 a, float4 b) {
    short8 r;
    r[0] = (short)f32_to_bf16(a.x); r[1] = (short)f32_to_bf16(a.y);
    r[2] = (short)f32_to_bf16(a.z); r[3] = (short)f32_to_bf16(a.w);
    r[4] = (short)f32_to_bf16(b.x); r[5] = (short)f32_to_bf16(b.y);
    r[6] = (short)f32_to_bf16(b.z); r[7] = (short)f32_to_bf16(b.w);
    return r;
}

// ---------------- K1: per-block coarse histogram -> dense coarse2d[blk][NC] ----------------
__global__ __launch_bounds__(512) void histC_kernel(const int* __restrict__ erow,
                                                    int* __restrict__ coarse2d, int ne) {
    __shared__ int h[NC];
    const int tid = threadIdx.x;
    if (tid < NC) h[tid] = 0;
    __syncthreads();
    const int base = blockIdx.x * PE;
    const int end  = min(base + PE, ne);
    for (int e = base + tid; e < end; e += 512)
        atomicAdd(&h[erow[e] >> 9], 1);              // LDS, no-return
    __syncthreads();
    if (tid < NC) coarse2d[blockIdx.x * NC + tid] = h[tid];
}

// ---------------- K2: scanA — per-1024-chunk exclusive scan (coarse-major) + chunk sums ----------------
__global__ __launch_bounds__(256) void scanA_kernel(const int* __restrict__ coarse2d,
                                                    int* __restrict__ csc,
                                                    int* __restrict__ bsum,
                                                    int total, int npb) {
    __shared__ int sdat[256];
    const int tid  = threadIdx.x;
    const int base = blockIdx.x * 1024 + tid * 4;
    int v[4], sum = 0;
    int C = 0, blk = 0;
    if (base < total) { C = base / npb; blk = base - C * npb; }
#pragma unroll
    for (int k = 0; k < 4; ++k) {
        const int idx = base + k;
        v[k] = (idx < total) ? coarse2d[blk * NC + C] : 0;
        sum += v[k];
        if (++blk == npb) { blk = 0; ++C; }
    }
    sdat[tid] = sum;
    __syncthreads();
    for (int d = 1; d < 256; d <<= 1) {
        const int t = (tid >= d) ? sdat[tid - d] : 0;
        __syncthreads();
        sdat[tid] += t;
        __syncthreads();
    }
    int run = sdat[tid] - sum;
#pragma unroll
    for (int k = 0; k < 4; ++k) {
        const int idx = base + k;
        if (idx < total) csc[idx] = run;
        run += v[k];
    }
    if (tid == 255) bsum[blockIdx.x] = sdat[255];
}

// ---------------- K3: fused  pass1 coarse scatter (blocks < npb)  ||  MFMA xw (blocks >= npb) ----------------
// pass1 blocks derive the bsum prefix themselves (<=128 chunk sums; no scanB launch)
__global__ __launch_bounds__(256) void xw_pass1_kernel(const float* __restrict__ x,
                                                       const float* __restrict__ W,
                                                       unsigned short* __restrict__ y,
                                                       const int* __restrict__ erow,
                                                       const int* __restrict__ ecol,
                                                       const float* __restrict__ eval_,
                                                       const int* __restrict__ csc,
                                                       const int* __restrict__ bsum,
                                                       uint2* __restrict__ pedge1,
                                                       int* __restrict__ cstart,
                                                       int ne, int npb, int nbA) {
    __shared__ int lcur[NC];                         // pass1 blocks only
    __shared__ int ps[128];                          // exclusive prefix of bsum chunks
    const int tid = threadIdx.x;

    if ((int)blockIdx.x < npb) {
        // ---- in-block exclusive scan of bsum (nbA <= 128) ----
        if (tid < 128) ps[tid] = (tid > 0 && tid - 1 < nbA) ? bsum[tid - 1] : 0;
        __syncthreads();
        for (int d = 1; d < 128; d <<= 1) {
            int t = 0;
            if (tid < 128 && tid >= d) t = ps[tid - d];
            __syncthreads();
            if (tid < 128) ps[tid] += t;
            __syncthreads();
        }

        // ---- pass1: coarse scatter, ~10-edge runs ----
        const int blk = blockIdx.x;
        if (tid < NC) {
            const int idx = tid * npb + blk;
            const int v = csc[idx] + ps[idx >> 10];
            lcur[tid] = v;
            if (blk == 0) cstart[tid] = v;           // coarse bucket global starts
        }
        if (blk == 0 && tid == 0) cstart[NC] = ne;
        __syncthreads();
        const int base = blk * PE;
        const int end  = min(base + PE, ne);
        for (int e = base + tid; e < end; e += 256) {
            const int r = erow[e];
            const int C = r >> 9;
            const int pos = atomicAdd(&lcur[C], 1);  // LDS-local rank
            int q = (int)(eval_[e] * 512.0f + 0.5f);
            q = (q > 511) ? 511 : q;
            uint2 pk;
            pk.x = ((u32)ecol[e] << 15) | ((u32)(r & 63) << 9) | (u32)q;
            pk.y = (u32)((r >> 6) & 7);              // fine bin within coarse bucket
            pedge1[pos] = pk;
        }
        return;
    }

    // ---- xw via MFMA (r16/r17-proven): 4 tiles per wave, no LDS ----
    const int gw = ((int)blockIdx.x - npb) * 4 + (tid >> 6);   // [0,1564)
    const int c  = tid & 15;
    const int q4 = (tid >> 4) & 3;

    const float4* Wv = (const float4*)W;
    short8 bfrag[4][2];
#pragma unroll
    for (int g = 0; g < 4; ++g) {
#pragma unroll
        for (int h = 0; h < 2; ++h) {
            const int bi = (16 * g + c) * 16 + 8 * h + 2 * q4;
            bfrag[g][h] = pack_bf16x8(Wv[bi], Wv[bi + 1]);
        }
    }

    const float4* Xv = (const float4*)x;
#pragma unroll
    for (int t = 0; t < 4; ++t) {
        const int tile = gw + 1564 * t;
        if (tile >= NTILES) break;
        const int n0 = tile * 16;

        const int ai = (n0 + c) * 16 + 2 * q4;
        const short8 a0 = pack_bf16x8(Xv[ai],     Xv[ai + 1]);       // k 0..31
        const short8 a1 = pack_bf16x8(Xv[ai + 8], Xv[ai + 9]);       // k 32..63

        f32x4 acc0 = {0.f, 0.f, 0.f, 0.f}, acc1 = acc0, acc2 = acc0, acc3 = acc0;
        acc0 = __builtin_amdgcn_mfma_f32_16x16x32_bf16(a0, bfrag[0][0], acc0, 0, 0, 0);
        acc1 = __builtin_amdgcn_mfma_f32_16x16x32_bf16(a0, bfrag[1][0], acc1, 0, 0, 0);
        acc2 = __builtin_amdgcn_mfma_f32_16x16x32_bf16(a0, bfrag[2][0], acc2, 0, 0, 0);
        acc3 = __builtin_amdgcn_mfma_f32_16x16x32_bf16(a0, bfrag[3][0], acc3, 0, 0, 0);
        acc0 = __builtin_amdgcn_mfma_f32_16x16x32_bf16(a1, bfrag[0][1], acc0, 0, 0, 0);
        acc1 = __builtin_amdgcn_mfma_f32_16x16x32_bf16(a1, bfrag[1][1], acc1, 0, 0, 0);
        acc2 = __builtin_amdgcn_mfma_f32_16x16x32_bf16(a1, bfrag[2][1], acc2, 0, 0, 0);
        acc3 = __builtin_amdgcn_mfma_f32_16x16x32_bf16(a1, bfrag[3][1], acc3, 0, 0, 0);

        const int rbase = n0 + q4 * 4;
#pragma unroll
        for (int r = 0; r < 4; ++r) {
            y[(rbase + r) * D +  0 + c] = f32_to_bf16(acc0[r]);
            y[(rbase + r) * D + 16 + c] = f32_to_bf16(acc1[r]);
            y[(rbase + r) * D + 32 + c] = f32_to_bf16(acc2[r]);
            y[(rbase + r) * D + 48 + c] = f32_to_bf16(acc3[r]);
        }
    }
}

// ---------------- K4: pass2 — per-coarse-bucket fine sort; derives binStart locally ----------------
__global__ __launch_bounds__(512) void pass2_kernel(const uint2* __restrict__ pedge1,
                                                    const int* __restrict__ cstart,
                                                    u32* __restrict__ pedge,
                                                    int* __restrict__ binStart) {
    __shared__ int fh[8];
    __shared__ int fcur[8];
    const int tid = threadIdx.x;
    const int C   = blockIdx.x;
    const int s   = cstart[C];
    const int e   = cstart[C + 1];

    if (tid < 8) fh[tid] = 0;
    __syncthreads();
    for (int i = s + tid; i < e; i += 512)
        atomicAdd(&fh[pedge1[i].y], 1);              // LDS, no-return
    __syncthreads();
    if (tid == 0) {
        int run = s;
#pragma unroll
        for (int j = 0; j < 8; ++j) {
            fcur[j] = run;
            binStart[8 * C + j] = run;
            run += fh[j];
        }
        binStart[8 * C + 8] = run;
    }
    __syncthreads();
    for (int i = s + tid; i < e; i += 512) {
        const uint2 p = pedge1[i];
        const int pos = atomicAdd(&fcur[p.y], 1);    // single-writer-per-bin, coalesced runs
        pedge[pos] = p.x;
    }
}

// ---------------- K5: aggregate — r17-proven 16-deep form, binStart offsets ----------------
__global__ __launch_bounds__(512) void aggregate_kernel(const int* __restrict__ binStart,
                                                        const u32* __restrict__ pedge,
                                                        const unsigned short* __restrict__ y,
                                                        const float* __restrict__ b,
                                                        float4* __restrict__ out4) {
    __shared__ int acc[BIN_ROWS * D];    // 16 KB
    const int tid = threadIdx.x;
    for (int i = tid; i < BIN_ROWS * D; i += 512) acc[i] = 0;
    __syncthreads();

    const int bin  = blockIdx.x;
    const int lane = tid & 63;
    const int w    = tid >> 6;           // 0..7
    const int s    = binStart[bin];
    const int e    = binStart[bin + 1];

    for (int bb0 = s + w * 16; bb0 < e; bb0 += 128) {
        const int bb = __builtin_amdgcn_readfirstlane(bb0);
        u32 u[16];
        if (bb + 16 <= e) {
#pragma unroll
            for (int j = 0; j < 16; ++j) u[j] = pedge[bb + j];   // uniform -> s_load
        } else {
#pragma unroll
            for (int j = 0; j < 16; ++j) {
                const int idx = bb + j;
                u[j] = (idx < e) ? pedge[idx] : 0u;              // pad adds 0
            }
        }
        unsigned short g[16];
#pragma unroll
        for (int j = 0; j < 16; ++j) {                           // 16 concurrent 128B gathers
            g[j] = y[(int)(u[j] >> 15) * D + lane];
        }
#pragma unroll
        for (int j = 0; j < 16; ++j) {
            const float vq = (float)(u[j] & 511u);               // val * 512
            const float yf = bf16_to_f32(g[j]);
            const int   qi = (int)(vq * yf * 512.0f);            // contribution * 2^18
            const int   r  = (int)((u[j] >> 9) & 63u);
            atomicAdd(&acc[r * D + lane], qi);                   // ds_add_u32 (native)
        }
    }
    __syncthreads();

    const int rowBase = bin * BIN_ROWS;
    const float INV = 1.0f / 262144.0f;
    for (int i = tid; i < BIN_ROWS * 16; i += 512) {
        const int rl = i >> 4, q = i & 15;
        const int row = rowBase + rl;
        if (row < N_NODES) {
            const int4   a  = ((const int4*)acc)[i];
            const float4 bv = ((const float4*)b)[q];
            out4[row * 16 + q] = make_float4((float)a.x * INV + bv.x,
                                             (float)a.y * INV + bv.y,
                                             (float)a.z * INV + bv.z,
                                             (float)a.w * INV + bv.w);
        }
    }
}

// ---------------- fallback (small ws): atomic scatter ----------------
__global__ __launch_bounds__(256) void init_out_kernel(const float* __restrict__ b,
                                                       float* __restrict__ out) {
    const int i = blockIdx.x * blockDim.x + threadIdx.x;
    const int total4 = N_NODES * D / 4;
    if (i < total4) {
        const float4* b4 = reinterpret_cast<const float4*>(b);
        reinterpret_cast<float4*>(out)[i] = b4[i & 15];
    }
}

__global__ __launch_bounds__(256) void scatter_kernel(const int* __restrict__ erow,
                                                      const int* __restrict__ ecol,
                                                      const float* __restrict__ eval_,
                                                      const unsigned short* __restrict__ y,
                                                      float* __restrict__ out, int ne) {
    const int e    = blockIdx.x * 4 + (threadIdx.x >> 6);
    const int lane = threadIdx.x & 63;
    if (e >= ne) return;
    atomicAdd(&out[erow[e] * D + lane], eval_[e] * bf16_to_f32(y[ecol[e] * D + lane]));
}

extern "C" void kernel_launch(void* const* d_in, const int* in_sizes, int n_in,
                              void* d_out, int out_size, void* d_ws, size_t ws_size,
                              hipStream_t stream) {
    const float* x     = (const float*)d_in[0];
    const int*   erow  = (const int*)  d_in[1];
    const int*   ecol  = (const int*)  d_in[2];
    const float* eval_ = (const float*)d_in[3];
    const float* W     = (const float*)d_in[4];
    const float* b     = (const float*)d_in[5];
    float*       out   = (float*)d_out;
    const int ne = in_sizes[1];

    char* ws = (char*)d_ws;
    // workspace layout (aligned)
    const size_t Y_OFF      = 0;            // 12,800,000 B
    const size_t PEDGE_OFF  = 12800000;     // 4,000,000 B (final u32)
    const size_t PEDGE1_OFF = 16800000;     // 8,000,000 B (coarse uint2)
    const size_t C2D_OFF    = 24800000;     // npb*NC*4 (<= 400,000 B)
    const size_t CSC_OFF    = 25200000;     // <= 400,000 B
    const size_t BSUM_OFF   = 25600000;     // 512 B
    const size_t CST_OFF    = 25600512;     // (NC+1)*4 -> 1,024 B
    const size_t BST_OFF    = 25601536;     // (8*NC+9)*4 -> 6,400 B
    const size_t TOTAL      = 25607936;

    unsigned short* y = (unsigned short*)(ws + Y_OFF);

    const int npb      = (ne + PE - 1) / PE;       // 489 @ 1M edges
    const int totalSc  = NC * npb;                 // 95,844
    const int nblocksA = (totalSc + 1023) / 1024;  // 94 (<= 128 for in-block prefix)

    if (ws_size >= TOTAL && npb <= 510 && ne <= 1000000 && nblocksA <= 128) {
        u32*   pedge    = (u32*)  (ws + PEDGE_OFF);
        uint2* pedge1   = (uint2*)(ws + PEDGE1_OFF);
        int*   coarse2d = (int*)  (ws + C2D_OFF);
        int*   csc      = (int*)  (ws + CSC_OFF);
        int*   bsum     = (int*)  (ws + BSUM_OFF);
        int*   cstart   = (int*)  (ws + CST_OFF);
        int*   binStart = (int*)  (ws + BST_OFF);

        // 1) per-block coarse histograms
        histC_kernel<<<npb, 512, 0, stream>>>(erow, coarse2d, ne);

        // 2) coarse-major exclusive scan (chunk-local; chunk prefix folded into pass1)
        scanA_kernel<<<nblocksA, 256, 0, stream>>>(coarse2d, csc, bsum, totalSc, npb);

        // 3) fused: pass1 coarse scatter (blocks [0,npb)) || MFMA xw (blocks [npb, npb+XB))
        xw_pass1_kernel<<<npb + XB, 256, 0, stream>>>(x, W, y, erow, ecol, eval_,
                                                      csc, bsum, pedge1, cstart, ne, npb, nblocksA);

        // 4) pass2: per-coarse-bucket fine sort (derives binStart)
        pass2_kernel<<<NC, 512, 0, stream>>>(pedge1, cstart, pedge, binStart);

        // 5) per-bin aggregation + bias
        aggregate_kernel<<<NBINS, 512, 0, stream>>>(binStart, pedge, y, b, (float4*)out);
    } else {
        xw_pass1_kernel<<<XB, 256, 0, stream>>>(x, W, y, erow, ecol, eval_,
                                                (int*)ws, (int*)ws, (uint2*)ws, (int*)ws, 0, 0, 0);
        init_out_kernel<<<(N_NODES * D / 4 + 255) / 256, 256, 0, stream>>>(b, out);
        scatter_kernel<<<(ne + 3) / 4, 256, 0, stream>>>(erow, ecol, eval_, y, out, ne);
    }
}